// Round 1
// baseline (151.127 us; speedup 1.0000x reference)
//
#include <hip/hip_runtime.h>

// Problem constants (fixed by the reference): B=8, H=320, W=1024, CH=CW=3, MAXINS=200
#define BATCH   8
#define HW      (320 * 1024)        // 327680 pixels per batch
#define ELEMS   (HW * 9)            // 2949120 floats per batch (divisible by 4)
#define MAXINS  200
#define BINS    (MAXINS * 9)        // 1800 floats = 7.2 KB

__global__ __launch_bounds__(256) void epp_compress(
    const int* __restrict__ inst, const float* __restrict__ src,
    float* __restrict__ comp)
{
    __shared__ float bins[BINS];
    const int b = blockIdx.y;

    for (int i = threadIdx.x; i < BINS; i += 256) bins[i] = 0.0f;
    __syncthreads();

    const int total4 = ELEMS / 4;                      // 737280 float4 per batch
    const int* __restrict__ instb = inst + b * HW;
    const float4* __restrict__ srcb =
        (const float4*)(src + (size_t)b * ELEMS);
    const int stride = gridDim.x * 256;

    for (int e4 = blockIdx.x * 256 + threadIdx.x; e4 < total4; e4 += stride) {
        float4 v = srcb[e4];
        const int e = e4 * 4;
        float vals[4] = {v.x, v.y, v.z, v.w};
#pragma unroll
        for (int k = 0; k < 4; ++k) {
            int ee  = e + k;
            int pix = ee / 9;                          // magic-mul division
            int j   = ee - pix * 9;
            int id  = instb[pix];
            atomicAdd(&bins[id * 9 + j], vals[k] * 1.1f);
        }
    }
    __syncthreads();

    float* __restrict__ compb = comp + b * BINS;
    for (int i = threadIdx.x; i < BINS; i += 256) {
        atomicAdd(&compb[i], bins[i]);
    }
}

__global__ __launch_bounds__(256) void epp_inflate(
    const int* __restrict__ inst, const float* __restrict__ comp,
    float* __restrict__ out)
{
    __shared__ float bins[BINS];
    const int b = blockIdx.y;

    // Stage the per-batch compressed table (7.2 KB) into LDS.
    const float* __restrict__ compb = comp + b * BINS;
    for (int i = threadIdx.x; i < BINS; i += 256) bins[i] = compb[i];
    __syncthreads();

    const int total4 = ELEMS / 4;
    const int* __restrict__ instb = inst + b * HW;
    float4* __restrict__ outb = (float4*)(out + (size_t)b * ELEMS);
    const int stride = gridDim.x * 256;

    for (int e4 = blockIdx.x * 256 + threadIdx.x; e4 < total4; e4 += stride) {
        const int e = e4 * 4;
        float vals[4];
#pragma unroll
        for (int k = 0; k < 4; ++k) {
            int ee  = e + k;
            int pix = ee / 9;
            int j   = ee - pix * 9;
            int id  = instb[pix];
            vals[k] = bins[id * 9 + j];
        }
        float4 v = {vals[0], vals[1], vals[2], vals[3]};
        outb[e4] = v;
    }
}

extern "C" void kernel_launch(void* const* d_in, const int* in_sizes, int n_in,
                              void* d_out, int out_size, void* d_ws, size_t ws_size,
                              hipStream_t stream) {
    const int*   inst = (const int*)d_in[0];    // [B,1,H,W] int32
    const float* src  = (const float*)d_in[1];  // [B,H,W,3,3] f32
    // d_in[2] = maxinsnum scalar (hardcoded to 200)
    float* out  = (float*)d_out;                // [B,H,W,3,3] f32
    float* comp = (float*)d_ws;                 // [B,200,9] f32 scratch

    // Zero the scatter-sum accumulator every call (determinism under graph replay).
    hipMemsetAsync(comp, 0, (size_t)BATCH * BINS * sizeof(float), stream);

    dim3 cgrid(128, BATCH);   // 1024 blocks, 4 blocks/CU, 16 waves/CU
    epp_compress<<<cgrid, 256, 0, stream>>>(inst, src, comp);

    dim3 igrid(256, BATCH);   // 2048 blocks
    epp_inflate<<<igrid, 256, 0, stream>>>(inst, comp, out);
}